// Round 17
// baseline (527.100 us; speedup 1.0000x reference)
//
#include <hip/hip_runtime.h>

// Adaptive softmax NLL — MX-fp8 (scaled 32x32x64 f8f6f4, unit scales) persistent
// GEMM, 256-thread/4-wave blocks shaped to R12's proven register budget:
// 64 AGPR acc (f32x16 acc[4]) + ~16 arch operand regs (af + one bf live).
// R12's verified memory system: row-major fp8 workspace, linear full-line
// convert, source-quarter swizzle q^((r>>1)&3), dual global_load_lds dbuf,
// cross-item prefetch, 4 blocks/CU. MX-MFMA semantics + epilogue layout
// verified in R15/R16 (absmax 0.125). Target/routing logits exact fp32.
//
// Weight chunks (128 rows x 512B): head 40, t1 79, t2 118, t3 159 (pad w=0,
// bias=-1e30, vanishes in exp-weighted LSE merges).
// Work item = (partition, chunk, token-tile), exact list, persistent CTAs.

#define D 512
#define NROWS_PAD 50688
#define NTOK 4096
#define NTOKP 4736
#define HEAD_CHUNKS 40
#define TAILP_STRIDE 160
#define GRID_PERSIST 1024

typedef __attribute__((ext_vector_type(4)))  float f32x4;
typedef __attribute__((ext_vector_type(16))) float f32x16;
typedef __attribute__((ext_vector_type(4)))  int   i32x4;
typedef __attribute__((ext_vector_type(8)))  int   i32x8;

__device__ __forceinline__ unsigned f2fp8(float f) {
    // f32 -> OCP e4m3fn, RNE, saturate to 448
    unsigned u = __float_as_uint(f);
    unsigned s = (u >> 24) & 0x80u;
    unsigned a = u & 0x7FFFFFFFu;
    if (a >= 0x43E00000u) return s | 0x7Eu;
    if (a < 0x3C800000u) {
        int n = __float2int_rn(__uint_as_float(a) * 512.f);
        return s | (unsigned)n;
    }
    unsigned lsb = (a >> 20) & 1u;
    a += 0x7FFFFu + lsb;
    unsigned e = (a >> 23) - 120u;
    unsigned m = (a >> 20) & 7u;
    if (e >= 16u || (e == 15u && m == 7u)) return s | 0x7Eu;
    return s | (e << 3) | m;
}

__device__ __forceinline__ void gload_lds16(const void* g, void* l) {
    __builtin_amdgcn_global_load_lds(
        (const __attribute__((address_space(1))) unsigned int*)g,
        (__attribute__((address_space(3))) unsigned int*)l, 16, 0, 0);
}

// ---------------- bucket tokens by cluster (deterministic counting sort) ----------------
__global__ __launch_bounds__(256) void k_bucket(
    const int* __restrict__ target, int* __restrict__ perm,
    int* __restrict__ inv, int* __restrict__ meta)
{
    __shared__ int cnt[256][4];
    __shared__ int basesh[256][4];
    __shared__ int sTot[4], sOff[4];
    const int th = threadIdx.x;
    for (int p = th; p < NTOKP; p += 256) perm[p] = -1;
    int lc[4] = {0, 0, 0, 0};
    #pragma unroll
    for (int i = 0; i < 16; ++i) {
        int tg = target[th * 16 + i];
        int c = (tg >= 5000) + (tg >= 15000) + (tg >= 30000);
        lc[c]++;
    }
    #pragma unroll
    for (int c = 0; c < 4; ++c) cnt[th][c] = lc[c];
    __syncthreads();
    if (th < 4) {
        int tot = 0;
        for (int i = 0; i < 256; ++i) tot += cnt[i][th];
        sTot[th] = tot;
    }
    __syncthreads();
    if (th == 0) {
        int b = 0;
        for (int c = 1; c < 4; ++c) { sOff[c] = b; b += ((sTot[c] + 127) >> 7) << 7; }
        meta[0] = sTot[1]; meta[1] = sTot[2]; meta[2] = sTot[3];
        meta[3] = sOff[1]; meta[4] = sOff[2]; meta[5] = sOff[3];
        meta[6] = (sTot[1] + 127) >> 7;
        meta[7] = (sTot[2] + 127) >> 7;
        meta[8] = (sTot[3] + 127) >> 7;
    }
    __syncthreads();
    if (th >= 1 && th < 4) {
        int run = sOff[th];
        for (int i = 0; i < 256; ++i) { basesh[i][th] = run; run += cnt[i][th]; }
    }
    __syncthreads();
    int run[4];
    #pragma unroll
    for (int c = 1; c < 4; ++c) run[c] = basesh[th][c];
    for (int i = 0; i < 16; ++i) {
        int t = th * 16 + i;
        int tg = target[t];
        int c = (tg >= 5000) + (tg >= 15000) + (tg >= 30000);
        if (c > 0) { int pos = run[c]++; perm[pos] = t; inv[t] = pos; }
        else inv[t] = -1;
    }
}

// ---------------- convert to fp8 (row-major, full-line writes) + fused stash ----------------
#define STASH_BASE (NROWS_PAD + NTOK + NTOKP)
__global__ __launch_bounds__(128) void k_convert(
    const float* __restrict__ weight, const float* __restrict__ bias,
    const float* __restrict__ cweight, const float* __restrict__ cbias,
    const float* __restrict__ hidden, const int* __restrict__ perm,
    const int* __restrict__ target,
    unsigned char* __restrict__ wsW, float* __restrict__ wsB,
    unsigned char* __restrict__ wsH, unsigned char* __restrict__ wsHc,
    float2* __restrict__ stash)
{
    const int r = blockIdx.x;
    const int i = threadIdx.x;   // 0..127
    if (r >= STASH_BASE) {
        // fused exact-fp32 stash: 2 waves/block, one token each
        const int wave = i >> 6, lane = i & 63;
        const int t = (r - STASH_BASE) * 2 + wave;
        const int tg = target[t];
        const int ci = (tg >= 5000) + (tg >= 15000) + (tg >= 30000);
        const float4* h = (const float4*)(hidden + (size_t)t * D);
        const float4* w = (const float4*)(weight + (size_t)tg * D);
        const float4* c = (const float4*)(cweight + (size_t)(ci ? 3 - ci : 0) * D);
        float dw = 0.f, dc = 0.f;
        #pragma unroll
        for (int u = 0; u < 2; ++u) {
            float4 hh = h[lane * 2 + u];
            float4 ww = w[lane * 2 + u];
            float4 cc = c[lane * 2 + u];
            dw += hh.x * ww.x + hh.y * ww.y + hh.z * ww.z + hh.w * ww.w;
            dc += hh.x * cc.x + hh.y * cc.y + hh.z * cc.z + hh.w * cc.w;
        }
        #pragma unroll
        for (int off = 1; off < 64; off <<= 1) {
            dw += __shfl_xor(dw, off, 64);
            dc += __shfl_xor(dc, off, 64);
        }
        if (lane == 0) {
            float head = ci ? dc + cbias[3 - ci] : dw + bias[tg];
            float tail = ci ? dw + bias[tg]      : 0.f;
            stash[t] = make_float2(head, tail);
        }
        return;
    }
    float4 v = make_float4(0.f, 0.f, 0.f, 0.f);
    unsigned* dst;
    if (r < NROWS_PAD) {
        const int pstart[4] = {0, 5120, 15232, 30336};
        const int plen[4]   = {5003, 10000, 15000, 20257};
        const int psrc[4]   = {0, 5000, 15000, 30000};
        int p = (r < 5120) ? 0 : (r < 15232) ? 1 : (r < 30336) ? 2 : 3;
        int o = r - pstart[p];
        const float* src = nullptr;
        float b = -1e30f;
        if (o < plen[p]) {
            if (p == 0 && o >= 5000) { src = cweight + (size_t)(o - 5000) * D; b = cbias[o - 5000]; }
            else { int sr = psrc[p] + o; src = weight + (size_t)sr * D; b = bias[sr]; }
        }
        if (src) v = ((const float4*)src)[i];
        if (i == 0) wsB[r] = b;
        dst = (unsigned*)(wsW + (size_t)r * D);
    } else if (r < NROWS_PAD + NTOK) {
        int hr = r - NROWS_PAD;
        v = ((const float4*)(hidden + (size_t)hr * D))[i];
        dst = (unsigned*)(wsH + (size_t)hr * D);
    } else {
        int p = r - NROWS_PAD - NTOK;       // compacted position
        int tok = perm[p];
        if (tok >= 0) v = ((const float4*)(hidden + (size_t)tok * D))[i];
        dst = (unsigned*)(wsHc + (size_t)p * D);
    }
    unsigned pk = f2fp8(v.x) | (f2fp8(v.y) << 8) | (f2fp8(v.z) << 16) | (f2fp8(v.w) << 24);
    dst[i] = pk;
}

// ---------------- persistent MX-fp8 GEMM: 128x128, BK=64, 4 waves, 4 blocks/CU ----------------
// Wave w owns rows [w*32,+32) x all 128 tokens: acc[4] f32x16 = 64 AGPRs;
// af (8) + one bf (8) live -> arch regs fit the 64-slot split (R12 shape).
__global__ __launch_bounds__(256, 4) void k_gemm_all(
    const unsigned char* __restrict__ wsW, const float* __restrict__ wsB,
    const unsigned char* __restrict__ wsH, const unsigned char* __restrict__ wsHc,
    float2* __restrict__ headP, float2* __restrict__ tailP,
    const int* __restrict__ meta)
{
    const int nt1 = meta[6], nt2 = meta[7], nt3 = meta[8];
    const int base1 = meta[3], base2 = meta[4], base3 = meta[5];
    const int b1 = HEAD_CHUNKS * 32;
    const int b2 = b1 + 79 * nt1;
    const int b3 = b2 + 118 * nt2;
    const int b4 = b3 + 159 * nt3;
    const unsigned SC1 = 0x7F7F7F7Fu;   // E8M0 unit scales (x1)

    const int tid = threadIdx.x;
    const int w = tid >> 6, lane = tid & 63;
    const int col = lane & 31, hi5 = lane >> 5;
    const int xq = (lane >> 1) & 3;                // (row>>1)&3, row ≡ lane (mod 8)
    const int g0off = ((hi5 * 2 + 0) ^ xq) * 16;   // 16B granules of 32B fragment
    const int g1off = ((hi5 * 2 + 1) ^ xq) * 16;
    const int aRow  = (w * 32 + col) * 64;         // A row byte base in LDS tile

    __shared__ __align__(16) unsigned char ldsA[2][8192];   // 128 rows x 64 B
    __shared__ __align__(16) unsigned char ldsB[2][8192];
    __shared__ float2 sred[4][128];

    auto decode = [&](int it, const unsigned char*& Wb, const unsigned char*& Hb,
                      int& p, int& chunk, int& tau, int& tokBase, int& rowBase) {
        if (it < b1)      { p = 0; chunk = it >> 5;          tau = it & 31;                 tokBase = 0; }
        else if (it < b2) { p = 1; int x = it - b1; chunk = x / nt1; tau = x - chunk * nt1; tokBase = base1; }
        else if (it < b3) { p = 2; int x = it - b2; chunk = x / nt2; tau = x - chunk * nt2; tokBase = base2; }
        else              { p = 3; int x = it - b3; chunk = x / nt3; tau = x - chunk * nt3; tokBase = base3; }
        const int pchunk_[4] = {0, 40, 119, 237};
        rowBase = (pchunk_[p] + chunk) * 128;
        Wb = wsW + (size_t)rowBase * D;
        Hb = (p == 0 ? wsH + (size_t)(tau * 128) * D
                     : wsHc + (size_t)(tokBase + tau * 128) * D);
    };

    auto STAGE = [&](const unsigned char* Wb, const unsigned char* Hb, int buf, int kt) {
        #pragma unroll
        for (int j = 0; j < 2; ++j) {
            int e = j * 256 + tid;              // 16-B granule slot, 0..511
            int r = e >> 2;                     // row 0..127
            int q = (e & 3) ^ ((r >> 1) & 3);   // inverse-swizzled source quarter
            size_t go = (size_t)r * D + (size_t)kt * 64 + q * 16;
            gload_lds16(Wb + go, &ldsA[buf][e * 16]);
            gload_lds16(Hb + go, &ldsB[buf][e * 16]);
        }
    };

    int item = blockIdx.x;
    if (item >= b4) return;

    const unsigned char *Wb, *Hb;
    int p, chunk, tau, tokBase, rowBase;
    decode(item, Wb, Hb, p, chunk, tau, tokBase, rowBase);
    STAGE(Wb, Hb, 0, 0);

    while (true) {
        const int nitem = item + GRID_PERSIST;
        const bool hasNext = nitem < b4;
        const unsigned char *nWb = nullptr, *nHb = nullptr;
        int np, nchunk, ntau, ntokBase, nrowBase;
        if (hasNext) decode(nitem, nWb, nHb, np, nchunk, ntau, ntokBase, nrowBase);

        f32x16 acc[4];
        #pragma unroll
        for (int tn = 0; tn < 4; ++tn)
            #pragma unroll
            for (int j = 0; j < 16; ++j) acc[tn][j] = 0.f;

        __syncthreads();                        // buf0 staged & drained; sred reusable

        for (int t = 0; t < 8; ++t) {
            const int buf = t & 1;
            if (t < 7) STAGE(Wb, Hb, buf ^ 1, t + 1);
            else if (hasNext) STAGE(nWb, nHb, 0, 0);   // prefetch next item tile 0
            const unsigned char* bA = &ldsA[buf][0];
            const unsigned char* bB = &ldsB[buf][0];
            i32x8 af;
            {
                i32x4 lo  = *(const i32x4*)(bA + aRow + g0off);
                i32x4 hiv = *(const i32x4*)(bA + aRow + g1off);
                af = __builtin_shufflevector(lo, hiv, 0, 1, 2, 3, 4, 5, 6, 7);
            }
            #pragma unroll
            for (int tn = 0; tn < 4; ++tn) {
                const int bRow = (tn * 32 + col) * 64;
                i32x4 lo  = *(const i32x4*)(bB + bRow + g0off);
                i32x4 hiv = *(const i32x4*)(bB + bRow + g1off);
                i32x8 bf = __builtin_shufflevector(lo, hiv, 0, 1, 2, 3, 4, 5, 6, 7);
                acc[tn] = __builtin_amdgcn_mfma_scale_f32_32x32x64_f8f6f4(
                    af, bf, acc[tn], 0, 0, 0, SC1, 0, SC1);
            }
            if (t < 7) __syncthreads();         // t=7 drains at epilogue barrier
        }

        // ---- epilogue: bias + per-token LSE over this wave's 32 rows ----
        // D layout (32x32): token = col, weight row = (reg&3) + 4*hi5 + 8*(reg>>2)
        #pragma unroll
        for (int tn = 0; tn < 4; ++tn) {
            float mval = -1e30f;
            #pragma unroll
            for (int q2 = 0; q2 < 4; ++q2) {
                f32x4 bbv = *(const f32x4*)(wsB + rowBase + w * 32 + q2 * 8 + hi5 * 4);
                #pragma unroll
                for (int j = 0; j < 4; ++j) {
                    acc[tn][q2 * 4 + j] += bbv[j];
                    mval = fmaxf(mval, acc[tn][q2 * 4 + j]);
                }
            }
            float sval = 0.f;
            #pragma unroll
            for (int j = 0; j < 16; ++j)
                sval += __expf(acc[tn][j] - mval);
            // merge lanes l <-> l+32 (same token, complementary rows)
            {
                float m2 = __shfl_xor(mval, 32, 64);
                float s2 = __shfl_xor(sval, 32, 64);
                float M = fmaxf(mval, m2);
                sval = sval * __expf(mval - M) + s2 * __expf(m2 - M);
                mval = M;
            }
            if (lane < 32)
                sred[w][tn * 32 + col] = make_float2(mval, sval);
        }
        __syncthreads();                        // also drains t=7 reads + prefetch
        if (tid < 128) {
            float2 p0 = sred[0][tid];
            #pragma unroll
            for (int q2 = 1; q2 < 4; ++q2) {
                float2 p1 = sred[q2][tid];
                float M = fmaxf(p0.x, p1.x);
                p0.y = p0.y * __expf(p0.x - M) + p1.y * __expf(p1.x - M);
                p0.x = M;
            }
            if (p == 0)
                headP[(size_t)(tau * 128 + tid) * HEAD_CHUNKS + chunk] = p0;
            else
                tailP[(size_t)(tokBase + tau * 128 + tid) * TAILP_STRIDE + chunk] = p0;
        }

        if (!hasNext) break;
        item = nitem;
        Wb = nWb; Hb = nHb;
        p = np; chunk = nchunk; tau = ntau; tokBase = ntokBase; rowBase = nrowBase;
    }
}

// ---------------- merge partials -> nll ----------------
__global__ __launch_bounds__(256) void k_stageB(
    const float2* __restrict__ headP, const float2* __restrict__ tailP,
    const float2* __restrict__ stash, const int* __restrict__ target,
    const int* __restrict__ inv, float* __restrict__ out)
{
    const int wave = threadIdx.x >> 6, lane = threadIdx.x & 63;
    const int t = blockIdx.x * 4 + wave;
    const int tg = target[t];
    const int ci = (tg >= 5000) + (tg >= 15000) + (tg >= 30000);

    float m = -1e30f, s = 0.f;
    if (lane < HEAD_CHUNKS) { float2 p = headP[(size_t)t * HEAD_CHUNKS + lane]; m = p.x; s = p.y; }
    #pragma unroll
    for (int off = 1; off < 64; off <<= 1) {
        float m2 = __shfl_xor(m, off, 64);
        float s2 = __shfl_xor(s, off, 64);
        float M = fmaxf(m, m2);
        s = s * __expf(m - M) + s2 * __expf(m2 - M);
        m = M;
    }
    float2 st = stash[t];
    float nll = (m + __logf(s)) - st.x;

    if (ci) {
        const int nch_[4] = {0, 79, 118, 159};
        const int nch = nch_[ci];
        const int pos = inv[t];
        float m2 = -1e30f, s2 = 0.f;
        for (int c = lane; c < nch; c += 64) {
            float2 p = tailP[(size_t)pos * TAILP_STRIDE + c];
            float M = fmaxf(m2, p.x);
            s2 = s2 * __expf(m2 - M) + p.y * __expf(p.x - M);
            m2 = M;
        }
        #pragma unroll
        for (int off = 1; off < 64; off <<= 1) {
            float mm = __shfl_xor(m2, off, 64);
            float ss = __shfl_xor(s2, off, 64);
            float M = fmaxf(m2, mm);
            s2 = s2 * __expf(m2 - M) + ss * __expf(mm - M);
            m2 = M;
        }
        nll += (m2 + __logf(s2)) - st.y;
    }
    if (lane == 0) out[t] = nll;
}

extern "C" void kernel_launch(void* const* d_in, const int* in_sizes, int n_in,
                              void* d_out, int out_size, void* d_ws, size_t ws_size,
                              hipStream_t stream) {
    const float* hidden  = (const float*)d_in[0];
    const int*   targetp = (const int*)d_in[1];
    const float* weight  = (const float*)d_in[2];
    const float* biasp   = (const float*)d_in[3];
    const float* cweight = (const float*)d_in[4];
    const float* cbias   = (const float*)d_in[5];
    float* outp = (float*)d_out;

    char* ws = (char*)d_ws;
    unsigned char* wsW   = (unsigned char*)(ws);                   // 25,952,256 B (fp8 row-major)
    float*         wsB   = (float*)(ws + 25952256);                //    202,752 B
    unsigned char* wsH   = (unsigned char*)(ws + 26155008);        //  2,097,152 B
    unsigned char* wsHc  = (unsigned char*)(ws + 28252160);        //  2,424,832 B
    float2*        headP = (float2*)(ws + 30676992);               //  1,310,720 B
    float2*        tailP = (float2*)(ws + 31987712);               //  6,062,080 B
    float2*        wsS   = (float2*)(ws + 38049792);               //     32,768 B
    int*           perm  = (int*)(ws + 38082560);                  //     18,944 B
    int*           inv   = (int*)(ws + 38101504);                  //     16,384 B
    int*           meta  = (int*)(ws + 38117888);                  //         64 B

    k_bucket<<<1, 256, 0, stream>>>(targetp, perm, inv, meta);
    k_convert<<<STASH_BASE + NTOK / 2, 128, 0, stream>>>(
        weight, biasp, cweight, cbias, hidden, perm, targetp,
        wsW, wsB, wsH, wsHc, wsS);
    k_gemm_all<<<GRID_PERSIST, 256, 0, stream>>>(wsW, wsB, wsH, wsHc, headP, tailP, meta);
    k_stageB<<<NTOK / 4, 256, 0, stream>>>(headP, tailP, wsS, targetp, inv, outp);
}

// Round 18
// 122.487 us; speedup vs baseline: 4.3033x; 4.3033x over previous
//
#include <hip/hip_runtime.h>

// Adaptive softmax NLL — fp8(e4m3)-MFMA persistent GEMM, 4 blocks/CU,
// cross-item prefetch. R12 champion + in-line 8B-unit permutation baked into
// the workspace (within each 64B K-window: unit u stored at u ^ ((row>>1)&7)).
// -> STAGE is linear (same byte traffic as R12), b64 fragment reads are
// bank-conflict-FREE (16-lane phase bijective onto 16 8B-slots).
// Target/routing logits exact fp32 (stash fused into k_convert, verified R15-17).
//
// Weight chunks (128 rows x 512B): head 40, t1 79, t2 118, t3 159 (pad w=0,
// bias=-1e30, vanishes in exp-weighted LSE merges).
// Work item = (partition, chunk, token-tile), exact list, persistent CTAs.

#define D 512
#define NROWS_PAD 50688
#define NTOK 4096
#define NTOKP 4736
#define HEAD_CHUNKS 40
#define TAILP_STRIDE 160
#define GRID_PERSIST 1024

typedef __attribute__((ext_vector_type(4))) float f32x4;

__device__ __forceinline__ unsigned f2fp8(float f) {
    // f32 -> OCP e4m3fn, RNE, saturate to 448
    unsigned u = __float_as_uint(f);
    unsigned s = (u >> 24) & 0x80u;
    unsigned a = u & 0x7FFFFFFFu;
    if (a >= 0x43E00000u) return s | 0x7Eu;          // >= 448 -> sat
    if (a < 0x3C800000u) {                            // < 2^-6 -> subnormal
        int n = __float2int_rn(__uint_as_float(a) * 512.f);
        return s | (unsigned)n;
    }
    unsigned lsb = (a >> 20) & 1u;
    a += 0x7FFFFu + lsb;                              // RNE at bit 20
    unsigned e = (a >> 23) - 120u;
    unsigned m = (a >> 20) & 7u;
    if (e >= 16u || (e == 15u && m == 7u)) return s | 0x7Eu;
    return s | (e << 3) | m;
}

__device__ __forceinline__ void gload_lds16(const void* g, void* l) {
    __builtin_amdgcn_global_load_lds(
        (const __attribute__((address_space(1))) unsigned int*)g,
        (__attribute__((address_space(3))) unsigned int*)l, 16, 0, 0);
}

// ---------------- bucket tokens by cluster (deterministic counting sort) ----------------
__global__ __launch_bounds__(256) void k_bucket(
    const int* __restrict__ target, int* __restrict__ perm,
    int* __restrict__ inv, int* __restrict__ meta)
{
    __shared__ int cnt[256][4];
    __shared__ int basesh[256][4];
    __shared__ int sTot[4], sOff[4];
    const int th = threadIdx.x;
    for (int p = th; p < NTOKP; p += 256) perm[p] = -1;
    int lc[4] = {0, 0, 0, 0};
    #pragma unroll
    for (int i = 0; i < 16; ++i) {
        int tg = target[th * 16 + i];
        int c = (tg >= 5000) + (tg >= 15000) + (tg >= 30000);
        lc[c]++;
    }
    #pragma unroll
    for (int c = 0; c < 4; ++c) cnt[th][c] = lc[c];
    __syncthreads();
    if (th < 4) {
        int tot = 0;
        for (int i = 0; i < 256; ++i) tot += cnt[i][th];
        sTot[th] = tot;
    }
    __syncthreads();
    if (th == 0) {
        int b = 0;
        for (int c = 1; c < 4; ++c) { sOff[c] = b; b += ((sTot[c] + 127) >> 7) << 7; }
        meta[0] = sTot[1]; meta[1] = sTot[2]; meta[2] = sTot[3];
        meta[3] = sOff[1]; meta[4] = sOff[2]; meta[5] = sOff[3];
        meta[6] = (sTot[1] + 127) >> 7;
        meta[7] = (sTot[2] + 127) >> 7;
        meta[8] = (sTot[3] + 127) >> 7;
    }
    __syncthreads();
    if (th >= 1 && th < 4) {
        int run = sOff[th];
        for (int i = 0; i < 256; ++i) { basesh[i][th] = run; run += cnt[i][th]; }
    }
    __syncthreads();
    int run[4];
    #pragma unroll
    for (int c = 1; c < 4; ++c) run[c] = basesh[th][c];
    for (int i = 0; i < 16; ++i) {
        int t = th * 16 + i;
        int tg = target[t];
        int c = (tg >= 5000) + (tg >= 15000) + (tg >= 30000);
        if (c > 0) { int pos = run[c]++; perm[pos] = t; inv[t] = pos; }
        else inv[t] = -1;
    }
}

// ---------------- convert to fp8 (permuted-in-window, full-line writes) + fused stash ----------------
// Dest u32 index within row: kt*16 + ((u_s ^ vr) * 2) + half, u_s=(i&15)>>1,
// half=i&1, kt=i>>4, vr=(r128>>1)&7. Permutation stays inside each 64B line.
#define STASH_BASE (NROWS_PAD + NTOK + NTOKP)
__global__ __launch_bounds__(128) void k_convert(
    const float* __restrict__ weight, const float* __restrict__ bias,
    const float* __restrict__ cweight, const float* __restrict__ cbias,
    const float* __restrict__ hidden, const int* __restrict__ perm,
    const int* __restrict__ target,
    unsigned char* __restrict__ wsW, float* __restrict__ wsB,
    unsigned char* __restrict__ wsH, unsigned char* __restrict__ wsHc,
    float2* __restrict__ stash)
{
    const int r = blockIdx.x;
    const int i = threadIdx.x;   // 0..127
    if (r >= STASH_BASE) {
        // fused exact-fp32 stash: 2 waves/block, one token each
        const int wave = i >> 6, lane = i & 63;
        const int t = (r - STASH_BASE) * 2 + wave;
        const int tg = target[t];
        const int ci = (tg >= 5000) + (tg >= 15000) + (tg >= 30000);
        const float4* h = (const float4*)(hidden + (size_t)t * D);
        const float4* w = (const float4*)(weight + (size_t)tg * D);
        const float4* c = (const float4*)(cweight + (size_t)(ci ? 3 - ci : 0) * D);
        float dw = 0.f, dc = 0.f;
        #pragma unroll
        for (int u = 0; u < 2; ++u) {
            float4 hh = h[lane * 2 + u];
            float4 ww = w[lane * 2 + u];
            float4 cc = c[lane * 2 + u];
            dw += hh.x * ww.x + hh.y * ww.y + hh.z * ww.z + hh.w * ww.w;
            dc += hh.x * cc.x + hh.y * cc.y + hh.z * cc.z + hh.w * cc.w;
        }
        #pragma unroll
        for (int off = 1; off < 64; off <<= 1) {
            dw += __shfl_xor(dw, off, 64);
            dc += __shfl_xor(dc, off, 64);
        }
        if (lane == 0) {
            float head = ci ? dc + cbias[3 - ci] : dw + bias[tg];
            float tail = ci ? dw + bias[tg]      : 0.f;
            stash[t] = make_float2(head, tail);
        }
        return;
    }
    float4 v = make_float4(0.f, 0.f, 0.f, 0.f);
    unsigned* dst;
    int r128;
    if (r < NROWS_PAD) {
        const int pstart[4] = {0, 5120, 15232, 30336};
        const int plen[4]   = {5003, 10000, 15000, 20257};
        const int psrc[4]   = {0, 5000, 15000, 30000};
        int p = (r < 5120) ? 0 : (r < 15232) ? 1 : (r < 30336) ? 2 : 3;
        int o = r - pstart[p];
        const float* src = nullptr;
        float b = -1e30f;
        if (o < plen[p]) {
            if (p == 0 && o >= 5000) { src = cweight + (size_t)(o - 5000) * D; b = cbias[o - 5000]; }
            else { int sr = psrc[p] + o; src = weight + (size_t)sr * D; b = bias[sr]; }
        }
        if (src) v = ((const float4*)src)[i];
        if (i == 0) wsB[r] = b;
        dst = (unsigned*)(wsW + (size_t)r * D);
        r128 = r & 127;
    } else if (r < NROWS_PAD + NTOK) {
        int hr = r - NROWS_PAD;
        v = ((const float4*)(hidden + (size_t)hr * D))[i];
        dst = (unsigned*)(wsH + (size_t)hr * D);
        r128 = hr & 127;
    } else {
        int p = r - NROWS_PAD - NTOK;       // compacted position
        int tok = perm[p];
        if (tok >= 0) v = ((const float4*)(hidden + (size_t)tok * D))[i];
        dst = (unsigned*)(wsHc + (size_t)p * D);
        r128 = p & 127;
    }
    unsigned pk = f2fp8(v.x) | (f2fp8(v.y) << 8) | (f2fp8(v.z) << 16) | (f2fp8(v.w) << 24);
    const int vr = (r128 >> 1) & 7;
    const int iw = (i >> 4) * 16 + ((((i & 15) >> 1) ^ vr) << 1) + (i & 1);
    dst[iw] = pk;
}

// ---------------- persistent fp8 GEMM: 128x128, BK=64, cross-item prefetch ----------------
// Linear STAGE (permutation baked in workspace); b64 fragment reads conflict-free:
// slot16 = 8*(r&1) + [(ks*4+kg) ^ ((lm>>1)&7)] bijective over each 16-lane phase.
__global__ __launch_bounds__(256, 4) void k_gemm_all(
    const unsigned char* __restrict__ wsW, const float* __restrict__ wsB,
    const unsigned char* __restrict__ wsH, const unsigned char* __restrict__ wsHc,
    float2* __restrict__ headP, float2* __restrict__ tailP,
    const int* __restrict__ meta)
{
    const int nt1 = meta[6], nt2 = meta[7], nt3 = meta[8];
    const int base1 = meta[3], base2 = meta[4], base3 = meta[5];
    const int b1 = HEAD_CHUNKS * 32;
    const int b2 = b1 + 79 * nt1;
    const int b3 = b2 + 118 * nt2;
    const int b4 = b3 + 159 * nt3;

    const int tid = threadIdx.x;
    const int w = tid >> 6, lane = tid & 63;
    const int wm = w >> 1, wn = w & 1;
    const int lm = lane & 15, kg = lane >> 4;
    const int v8 = (lm >> 1) & 7;              // per-lane unit-XOR (row ≡ lm mod 16)
    const int rowA = wm * 64 + lm;
    const int rowB = wn * 64 + lm;
    const int koff0 = ((0 * 4 + kg) ^ v8) * 8; // ks=0 fragment byte offset in 64B window
    const int koff1 = ((1 * 4 + kg) ^ v8) * 8; // ks=1

    __shared__ __align__(16) unsigned char ldsA[2][8192];   // 128 rows x 64 B (fp8, BK=64)
    __shared__ __align__(16) unsigned char ldsB[2][8192];
    __shared__ float2 sred[2][128];

    auto decode = [&](int it, const unsigned char*& Wb, const unsigned char*& Hb,
                      int& p, int& chunk, int& tau, int& tokBase, int& rowBase) {
        if (it < b1)      { p = 0; chunk = it >> 5;          tau = it & 31;                 tokBase = 0; }
        else if (it < b2) { p = 1; int x = it - b1; chunk = x / nt1; tau = x - chunk * nt1; tokBase = base1; }
        else if (it < b3) { p = 2; int x = it - b2; chunk = x / nt2; tau = x - chunk * nt2; tokBase = base2; }
        else              { p = 3; int x = it - b3; chunk = x / nt3; tau = x - chunk * nt3; tokBase = base3; }
        const int pchunk_[4] = {0, 40, 119, 237};
        rowBase = (pchunk_[p] + chunk) * 128;
        Wb = wsW + (size_t)rowBase * D;
        Hb = (p == 0 ? wsH + (size_t)(tau * 128) * D
                     : wsHc + (size_t)(tokBase + tau * 128) * D);
    };

    auto STAGE = [&](const unsigned char* Wb, const unsigned char* Hb, int buf, int kt) {
        #pragma unroll
        for (int j = 0; j < 2; ++j) {
            int e = j * 256 + tid;              // linear 16-B granule copy, 0..511
            int r = e >> 2;                     // row 0..127
            size_t go = (size_t)r * D + (size_t)kt * 64 + (e & 3) * 16;
            gload_lds16(Wb + go, &ldsA[buf][e * 16]);
            gload_lds16(Hb + go, &ldsB[buf][e * 16]);
        }
    };

    int item = blockIdx.x;
    if (item >= b4) return;

    const unsigned char *Wb, *Hb;
    int p, chunk, tau, tokBase, rowBase;
    decode(item, Wb, Hb, p, chunk, tau, tokBase, rowBase);
    STAGE(Wb, Hb, 0, 0);

    while (true) {
        const int nitem = item + GRID_PERSIST;
        const bool hasNext = nitem < b4;
        const unsigned char *nWb = nullptr, *nHb = nullptr;
        int np, nchunk, ntau, ntokBase, nrowBase;
        if (hasNext) decode(nitem, nWb, nHb, np, nchunk, ntau, ntokBase, nrowBase);

        f32x4 acc[4][4];
        #pragma unroll
        for (int m = 0; m < 4; ++m)
            #pragma unroll
            for (int n = 0; n < 4; ++n) acc[m][n] = (f32x4){0.f, 0.f, 0.f, 0.f};

        __syncthreads();                        // buf0 staged & drained; sred reusable

        for (int t = 0; t < 8; ++t) {
            const int buf = t & 1;
            if (t < 7) STAGE(Wb, Hb, buf ^ 1, t + 1);
            else if (hasNext) STAGE(nWb, nHb, 0, 0);   // prefetch next item tile 0
            const char* bA = (const char*)&ldsA[buf][0];
            const char* bB = (const char*)&ldsB[buf][0];
            #pragma unroll
            for (int ks = 0; ks < 2; ++ks) {
                const int koff = ks ? koff1 : koff0;
                long af[4], bf8[4];
                #pragma unroll
                for (int m = 0; m < 4; ++m)
                    af[m] = *(const long*)(bA + (rowA + m * 16) * 64 + koff);
                #pragma unroll
                for (int n = 0; n < 4; ++n)
                    bf8[n] = *(const long*)(bB + (rowB + n * 16) * 64 + koff);
                #pragma unroll
                for (int m = 0; m < 4; ++m)
                    #pragma unroll
                    for (int n = 0; n < 4; ++n)
                        acc[m][n] = __builtin_amdgcn_mfma_f32_16x16x32_fp8_fp8(
                            af[m], bf8[n], acc[m][n], 0, 0, 0);
            }
            if (t < 7) __syncthreads();         // t=7 drains at epilogue barrier
        }

        // ---- epilogue: bias + per-token LSE over this chunk's 128 rows ----
        f32x4 bb[4];
        #pragma unroll
        for (int m = 0; m < 4; ++m)
            bb[m] = *(const f32x4*)(wsB + rowBase + wm * 64 + m * 16 + kg * 4);

        #pragma unroll
        for (int n = 0; n < 4; ++n) {
            float mval = -1e30f;
            #pragma unroll
            for (int m = 0; m < 4; ++m)
                #pragma unroll
                for (int j = 0; j < 4; ++j) {
                    acc[m][n][j] += bb[m][j];
                    mval = fmaxf(mval, acc[m][n][j]);
                }
            float sval = 0.f;
            #pragma unroll
            for (int m = 0; m < 4; ++m)
                #pragma unroll
                for (int j = 0; j < 4; ++j)
                    sval += __expf(acc[m][n][j] - mval);
            #pragma unroll
            for (int off = 16; off < 64; off <<= 1) {
                float m2 = __shfl_xor(mval, off, 64);
                float s2 = __shfl_xor(sval, off, 64);
                float M = fmaxf(mval, m2);
                sval = sval * __expf(mval - M) + s2 * __expf(m2 - M);
                mval = M;
            }
            if (lane < 16)
                sred[wm][wn * 64 + n * 16 + lane] = make_float2(mval, sval);
        }
        __syncthreads();                        // also drains t=7 reads + prefetch
        if (tid < 128) {
            float2 p0 = sred[0][tid], p1 = sred[1][tid];
            float M = fmaxf(p0.x, p1.x);
            float S = p0.y * __expf(p0.x - M) + p1.y * __expf(p1.x - M);
            if (p == 0)
                headP[(size_t)(tau * 128 + tid) * HEAD_CHUNKS + chunk] = make_float2(M, S);
            else
                tailP[(size_t)(tokBase + tau * 128 + tid) * TAILP_STRIDE + chunk] = make_float2(M, S);
        }

        if (!hasNext) break;
        item = nitem;
        Wb = nWb; Hb = nHb;
        p = np; chunk = nchunk; tau = ntau; tokBase = ntokBase; rowBase = nrowBase;
    }
}

// ---------------- merge partials -> nll ----------------
__global__ __launch_bounds__(256) void k_stageB(
    const float2* __restrict__ headP, const float2* __restrict__ tailP,
    const float2* __restrict__ stash, const int* __restrict__ target,
    const int* __restrict__ inv, float* __restrict__ out)
{
    const int wave = threadIdx.x >> 6, lane = threadIdx.x & 63;
    const int t = blockIdx.x * 4 + wave;
    const int tg = target[t];
    const int ci = (tg >= 5000) + (tg >= 15000) + (tg >= 30000);

    float m = -1e30f, s = 0.f;
    if (lane < HEAD_CHUNKS) { float2 p = headP[(size_t)t * HEAD_CHUNKS + lane]; m = p.x; s = p.y; }
    #pragma unroll
    for (int off = 1; off < 64; off <<= 1) {
        float m2 = __shfl_xor(m, off, 64);
        float s2 = __shfl_xor(s, off, 64);
        float M = fmaxf(m, m2);
        s = s * __expf(m - M) + s2 * __expf(m2 - M);
        m = M;
    }
    float2 st = stash[t];
    float nll = (m + __logf(s)) - st.x;

    if (ci) {
        const int nch_[4] = {0, 79, 118, 159};
        const int nch = nch_[ci];
        const int pos = inv[t];
        float m2 = -1e30f, s2 = 0.f;
        for (int c = lane; c < nch; c += 64) {
            float2 p = tailP[(size_t)pos * TAILP_STRIDE + c];
            float M = fmaxf(m2, p.x);
            s2 = s2 * __expf(m2 - M) + p.y * __expf(p.x - M);
            m2 = M;
        }
        #pragma unroll
        for (int off = 1; off < 64; off <<= 1) {
            float mm = __shfl_xor(m2, off, 64);
            float ss = __shfl_xor(s2, off, 64);
            float M = fmaxf(m2, mm);
            s2 = s2 * __expf(m2 - M) + ss * __expf(mm - M);
            m2 = M;
        }
        nll += (m2 + __logf(s2)) - st.y;
    }
    if (lane == 0) out[t] = nll;
}

extern "C" void kernel_launch(void* const* d_in, const int* in_sizes, int n_in,
                              void* d_out, int out_size, void* d_ws, size_t ws_size,
                              hipStream_t stream) {
    const float* hidden  = (const float*)d_in[0];
    const int*   targetp = (const int*)d_in[1];
    const float* weight  = (const float*)d_in[2];
    const float* biasp   = (const float*)d_in[3];
    const float* cweight = (const float*)d_in[4];
    const float* cbias   = (const float*)d_in[5];
    float* outp = (float*)d_out;

    char* ws = (char*)d_ws;
    unsigned char* wsW   = (unsigned char*)(ws);                   // 25,952,256 B (fp8 permuted-in-window)
    float*         wsB   = (float*)(ws + 25952256);                //    202,752 B
    unsigned char* wsH   = (unsigned char*)(ws + 26155008);        //  2,097,152 B
    unsigned char* wsHc  = (unsigned char*)(ws + 28252160);        //  2,424,832 B
    float2*        headP = (float2*)(ws + 30676992);               //  1,310,720 B
    float2*        tailP = (float2*)(ws + 31987712);               //  6,062,080 B
    float2*        wsS   = (float2*)(ws + 38049792);               //     32,768 B
    int*           perm  = (int*)(ws + 38082560);                  //     18,944 B
    int*           inv   = (int*)(ws + 38101504);                  //     16,384 B
    int*           meta  = (int*)(ws + 38117888);                  //         64 B

    k_bucket<<<1, 256, 0, stream>>>(targetp, perm, inv, meta);
    k_convert<<<STASH_BASE + NTOK / 2, 128, 0, stream>>>(
        weight, biasp, cweight, cbias, hidden, perm, targetp,
        wsW, wsB, wsH, wsHc, wsS);
    k_gemm_all<<<GRID_PERSIST, 256, 0, stream>>>(wsW, wsB, wsH, wsHc, headP, tailP, meta);
    k_stageB<<<NTOK / 4, 256, 0, stream>>>(headP, tailP, wsS, targetp, inv, outp);
}

// Round 19
// 120.760 us; speedup vs baseline: 4.3648x; 1.0143x over previous
//
#include <hip/hip_runtime.h>

// Adaptive softmax NLL — fp8(e4m3)-MFMA persistent GEMM, 4 blocks/CU,
// cross-item prefetch, workspace-baked 8B-unit permutation (0 LDS conflicts),
// XCD-CONTIGUOUS persistent item assignment (each XCD owns a contiguous,
// equal-size slice of the exact item list -> weight slab L2-resident per XCD).
// Target/routing logits exact fp32 (stash fused into k_convert).
//
// Weight chunks (128 rows x 512B): head 40, t1 79, t2 118, t3 159 (pad w=0,
// bias=-1e30, vanishes in exp-weighted LSE merges).
// Work item = (partition, chunk, token-tile), exact list, persistent CTAs.

#define D 512
#define NROWS_PAD 50688
#define NTOK 4096
#define NTOKP 4736
#define HEAD_CHUNKS 40
#define TAILP_STRIDE 160
#define GRID_PERSIST 1024

typedef __attribute__((ext_vector_type(4))) float f32x4;

__device__ __forceinline__ unsigned f2fp8(float f) {
    // f32 -> OCP e4m3fn, RNE, saturate to 448
    unsigned u = __float_as_uint(f);
    unsigned s = (u >> 24) & 0x80u;
    unsigned a = u & 0x7FFFFFFFu;
    if (a >= 0x43E00000u) return s | 0x7Eu;          // >= 448 -> sat
    if (a < 0x3C800000u) {                            // < 2^-6 -> subnormal
        int n = __float2int_rn(__uint_as_float(a) * 512.f);
        return s | (unsigned)n;
    }
    unsigned lsb = (a >> 20) & 1u;
    a += 0x7FFFFu + lsb;                              // RNE at bit 20
    unsigned e = (a >> 23) - 120u;
    unsigned m = (a >> 20) & 7u;
    if (e >= 16u || (e == 15u && m == 7u)) return s | 0x7Eu;
    return s | (e << 3) | m;
}

__device__ __forceinline__ void gload_lds16(const void* g, void* l) {
    __builtin_amdgcn_global_load_lds(
        (const __attribute__((address_space(1))) unsigned int*)g,
        (__attribute__((address_space(3))) unsigned int*)l, 16, 0, 0);
}

// ---------------- bucket tokens by cluster (deterministic counting sort) ----------------
__global__ __launch_bounds__(256) void k_bucket(
    const int* __restrict__ target, int* __restrict__ perm,
    int* __restrict__ inv, int* __restrict__ meta)
{
    __shared__ int cnt[256][4];
    __shared__ int basesh[256][4];
    __shared__ int sTot[4], sOff[4];
    const int th = threadIdx.x;
    for (int p = th; p < NTOKP; p += 256) perm[p] = -1;
    int lc[4] = {0, 0, 0, 0};
    #pragma unroll
    for (int i = 0; i < 16; ++i) {
        int tg = target[th * 16 + i];
        int c = (tg >= 5000) + (tg >= 15000) + (tg >= 30000);
        lc[c]++;
    }
    #pragma unroll
    for (int c = 0; c < 4; ++c) cnt[th][c] = lc[c];
    __syncthreads();
    if (th < 4) {
        int tot = 0;
        for (int i = 0; i < 256; ++i) tot += cnt[i][th];
        sTot[th] = tot;
    }
    __syncthreads();
    if (th == 0) {
        int b = 0;
        for (int c = 1; c < 4; ++c) { sOff[c] = b; b += ((sTot[c] + 127) >> 7) << 7; }
        meta[0] = sTot[1]; meta[1] = sTot[2]; meta[2] = sTot[3];
        meta[3] = sOff[1]; meta[4] = sOff[2]; meta[5] = sOff[3];
        meta[6] = (sTot[1] + 127) >> 7;
        meta[7] = (sTot[2] + 127) >> 7;
        meta[8] = (sTot[3] + 127) >> 7;
    }
    __syncthreads();
    if (th >= 1 && th < 4) {
        int run = sOff[th];
        for (int i = 0; i < 256; ++i) { basesh[i][th] = run; run += cnt[i][th]; }
    }
    __syncthreads();
    int run[4];
    #pragma unroll
    for (int c = 1; c < 4; ++c) run[c] = basesh[th][c];
    for (int i = 0; i < 16; ++i) {
        int t = th * 16 + i;
        int tg = target[t];
        int c = (tg >= 5000) + (tg >= 15000) + (tg >= 30000);
        if (c > 0) { int pos = run[c]++; perm[pos] = t; inv[t] = pos; }
        else inv[t] = -1;
    }
}

// ---------------- convert to fp8 (permuted-in-window, full-line writes) + fused stash ----------------
// Dest u32 index within row: kt*16 + ((u_s ^ vr) * 2) + half, u_s=(i&15)>>1,
// half=i&1, kt=i>>4, vr=(r128>>1)&7. Permutation stays inside each 64B line.
#define STASH_BASE (NROWS_PAD + NTOK + NTOKP)
__global__ __launch_bounds__(128) void k_convert(
    const float* __restrict__ weight, const float* __restrict__ bias,
    const float* __restrict__ cweight, const float* __restrict__ cbias,
    const float* __restrict__ hidden, const int* __restrict__ perm,
    const int* __restrict__ target,
    unsigned char* __restrict__ wsW, float* __restrict__ wsB,
    unsigned char* __restrict__ wsH, unsigned char* __restrict__ wsHc,
    float2* __restrict__ stash)
{
    const int r = blockIdx.x;
    const int i = threadIdx.x;   // 0..127
    if (r >= STASH_BASE) {
        // fused exact-fp32 stash: 2 waves/block, one token each
        const int wave = i >> 6, lane = i & 63;
        const int t = (r - STASH_BASE) * 2 + wave;
        const int tg = target[t];
        const int ci = (tg >= 5000) + (tg >= 15000) + (tg >= 30000);
        const float4* h = (const float4*)(hidden + (size_t)t * D);
        const float4* w = (const float4*)(weight + (size_t)tg * D);
        const float4* c = (const float4*)(cweight + (size_t)(ci ? 3 - ci : 0) * D);
        float dw = 0.f, dc = 0.f;
        #pragma unroll
        for (int u = 0; u < 2; ++u) {
            float4 hh = h[lane * 2 + u];
            float4 ww = w[lane * 2 + u];
            float4 cc = c[lane * 2 + u];
            dw += hh.x * ww.x + hh.y * ww.y + hh.z * ww.z + hh.w * ww.w;
            dc += hh.x * cc.x + hh.y * cc.y + hh.z * cc.z + hh.w * cc.w;
        }
        #pragma unroll
        for (int off = 1; off < 64; off <<= 1) {
            dw += __shfl_xor(dw, off, 64);
            dc += __shfl_xor(dc, off, 64);
        }
        if (lane == 0) {
            float head = ci ? dc + cbias[3 - ci] : dw + bias[tg];
            float tail = ci ? dw + bias[tg]      : 0.f;
            stash[t] = make_float2(head, tail);
        }
        return;
    }
    float4 v = make_float4(0.f, 0.f, 0.f, 0.f);
    unsigned* dst;
    int r128;
    if (r < NROWS_PAD) {
        const int pstart[4] = {0, 5120, 15232, 30336};
        const int plen[4]   = {5003, 10000, 15000, 20257};
        const int psrc[4]   = {0, 5000, 15000, 30000};
        int p = (r < 5120) ? 0 : (r < 15232) ? 1 : (r < 30336) ? 2 : 3;
        int o = r - pstart[p];
        const float* src = nullptr;
        float b = -1e30f;
        if (o < plen[p]) {
            if (p == 0 && o >= 5000) { src = cweight + (size_t)(o - 5000) * D; b = cbias[o - 5000]; }
            else { int sr = psrc[p] + o; src = weight + (size_t)sr * D; b = bias[sr]; }
        }
        if (src) v = ((const float4*)src)[i];
        if (i == 0) wsB[r] = b;
        dst = (unsigned*)(wsW + (size_t)r * D);
        r128 = r & 127;
    } else if (r < NROWS_PAD + NTOK) {
        int hr = r - NROWS_PAD;
        v = ((const float4*)(hidden + (size_t)hr * D))[i];
        dst = (unsigned*)(wsH + (size_t)hr * D);
        r128 = hr & 127;
    } else {
        int p = r - NROWS_PAD - NTOK;       // compacted position
        int tok = perm[p];
        if (tok >= 0) v = ((const float4*)(hidden + (size_t)tok * D))[i];
        dst = (unsigned*)(wsHc + (size_t)p * D);
        r128 = p & 127;
    }
    unsigned pk = f2fp8(v.x) | (f2fp8(v.y) << 8) | (f2fp8(v.z) << 16) | (f2fp8(v.w) << 24);
    const int vr = (r128 >> 1) & 7;
    const int iw = (i >> 4) * 16 + ((((i & 15) >> 1) ^ vr) << 1) + (i & 1);
    dst[iw] = pk;
}

// ---------------- persistent fp8 GEMM: 128x128, BK=64, XCD-contiguous items ----------------
// Linear STAGE (permutation baked in workspace); b64 fragment reads conflict-free.
// Block b -> (xcd = b&7, slot = b>>3); XCD x owns items [x*nper, (x+1)*nper),
// strided by 128 slots -> equal per-XCD load, weight slab L2-resident per XCD.
__global__ __launch_bounds__(256, 4) void k_gemm_all(
    const unsigned char* __restrict__ wsW, const float* __restrict__ wsB,
    const unsigned char* __restrict__ wsH, const unsigned char* __restrict__ wsHc,
    float2* __restrict__ headP, float2* __restrict__ tailP,
    const int* __restrict__ meta)
{
    const int nt1 = meta[6], nt2 = meta[7], nt3 = meta[8];
    const int base1 = meta[3], base2 = meta[4], base3 = meta[5];
    const int b1 = HEAD_CHUNKS * 32;
    const int b2 = b1 + 79 * nt1;
    const int b3 = b2 + 118 * nt2;
    const int b4 = b3 + 159 * nt3;

    const int tid = threadIdx.x;
    const int w = tid >> 6, lane = tid & 63;
    const int wm = w >> 1, wn = w & 1;
    const int lm = lane & 15, kg = lane >> 4;
    const int v8 = (lm >> 1) & 7;              // per-lane unit-XOR (row ≡ lm mod 16)
    const int rowA = wm * 64 + lm;
    const int rowB = wn * 64 + lm;
    const int koff0 = ((0 * 4 + kg) ^ v8) * 8; // ks=0 fragment byte offset in 64B window
    const int koff1 = ((1 * 4 + kg) ^ v8) * 8; // ks=1

    __shared__ __align__(16) unsigned char ldsA[2][8192];   // 128 rows x 64 B (fp8, BK=64)
    __shared__ __align__(16) unsigned char ldsB[2][8192];
    __shared__ float2 sred[2][128];

    auto decode = [&](int it, const unsigned char*& Wb, const unsigned char*& Hb,
                      int& p, int& chunk, int& tau, int& tokBase, int& rowBase) {
        if (it < b1)      { p = 0; chunk = it >> 5;          tau = it & 31;                 tokBase = 0; }
        else if (it < b2) { p = 1; int x = it - b1; chunk = x / nt1; tau = x - chunk * nt1; tokBase = base1; }
        else if (it < b3) { p = 2; int x = it - b2; chunk = x / nt2; tau = x - chunk * nt2; tokBase = base2; }
        else              { p = 3; int x = it - b3; chunk = x / nt3; tau = x - chunk * nt3; tokBase = base3; }
        const int pchunk_[4] = {0, 40, 119, 237};
        rowBase = (pchunk_[p] + chunk) * 128;
        Wb = wsW + (size_t)rowBase * D;
        Hb = (p == 0 ? wsH + (size_t)(tau * 128) * D
                     : wsHc + (size_t)(tokBase + tau * 128) * D);
    };

    auto STAGE = [&](const unsigned char* Wb, const unsigned char* Hb, int buf, int kt) {
        #pragma unroll
        for (int j = 0; j < 2; ++j) {
            int e = j * 256 + tid;              // linear 16-B granule copy, 0..511
            int r = e >> 2;                     // row 0..127
            size_t go = (size_t)r * D + (size_t)kt * 64 + (e & 3) * 16;
            gload_lds16(Wb + go, &ldsA[buf][e * 16]);
            gload_lds16(Hb + go, &ldsB[buf][e * 16]);
        }
    };

    // XCD-contiguous item slice
    const int nper = (b4 + 7) >> 3;
    const int xcd = blockIdx.x & 7;
    const int slot = blockIdx.x >> 3;          // 0..127 slots per XCD
    int k = slot;
    int item = xcd * nper + k;
    if (k >= nper || item >= b4) return;

    const unsigned char *Wb, *Hb;
    int p, chunk, tau, tokBase, rowBase;
    decode(item, Wb, Hb, p, chunk, tau, tokBase, rowBase);
    STAGE(Wb, Hb, 0, 0);

    while (true) {
        const int nk = k + 128;
        const int nitem = xcd * nper + nk;
        const bool hasNext = (nk < nper) && (nitem < b4);
        const unsigned char *nWb = nullptr, *nHb = nullptr;
        int np, nchunk, ntau, ntokBase, nrowBase;
        if (hasNext) decode(nitem, nWb, nHb, np, nchunk, ntau, ntokBase, nrowBase);

        f32x4 acc[4][4];
        #pragma unroll
        for (int m = 0; m < 4; ++m)
            #pragma unroll
            for (int n = 0; n < 4; ++n) acc[m][n] = (f32x4){0.f, 0.f, 0.f, 0.f};

        __syncthreads();                        // buf0 staged & drained; sred reusable

        for (int t = 0; t < 8; ++t) {
            const int buf = t & 1;
            if (t < 7) STAGE(Wb, Hb, buf ^ 1, t + 1);
            else if (hasNext) STAGE(nWb, nHb, 0, 0);   // prefetch next item tile 0
            const char* bA = (const char*)&ldsA[buf][0];
            const char* bB = (const char*)&ldsB[buf][0];
            #pragma unroll
            for (int ks = 0; ks < 2; ++ks) {
                const int koff = ks ? koff1 : koff0;
                long af[4], bf8[4];
                #pragma unroll
                for (int m = 0; m < 4; ++m)
                    af[m] = *(const long*)(bA + (rowA + m * 16) * 64 + koff);
                #pragma unroll
                for (int n = 0; n < 4; ++n)
                    bf8[n] = *(const long*)(bB + (rowB + n * 16) * 64 + koff);
                #pragma unroll
                for (int m = 0; m < 4; ++m)
                    #pragma unroll
                    for (int n = 0; n < 4; ++n)
                        acc[m][n] = __builtin_amdgcn_mfma_f32_16x16x32_fp8_fp8(
                            af[m], bf8[n], acc[m][n], 0, 0, 0);
            }
            if (t < 7) __syncthreads();         // t=7 drains at epilogue barrier
        }

        // ---- epilogue: bias + per-token LSE over this chunk's 128 rows ----
        f32x4 bb[4];
        #pragma unroll
        for (int m = 0; m < 4; ++m)
            bb[m] = *(const f32x4*)(wsB + rowBase + wm * 64 + m * 16 + kg * 4);

        #pragma unroll
        for (int n = 0; n < 4; ++n) {
            float mval = -1e30f;
            #pragma unroll
            for (int m = 0; m < 4; ++m)
                #pragma unroll
                for (int j = 0; j < 4; ++j) {
                    acc[m][n][j] += bb[m][j];
                    mval = fmaxf(mval, acc[m][n][j]);
                }
            float sval = 0.f;
            #pragma unroll
            for (int m = 0; m < 4; ++m)
                #pragma unroll
                for (int j = 0; j < 4; ++j)
                    sval += __expf(acc[m][n][j] - mval);
            #pragma unroll
            for (int off = 16; off < 64; off <<= 1) {
                float m2 = __shfl_xor(mval, off, 64);
                float s2 = __shfl_xor(sval, off, 64);
                float M = fmaxf(mval, m2);
                sval = sval * __expf(mval - M) + s2 * __expf(m2 - M);
                mval = M;
            }
            if (lane < 16)
                sred[wm][wn * 64 + n * 16 + lane] = make_float2(mval, sval);
        }
        __syncthreads();                        // also drains t=7 reads + prefetch
        if (tid < 128) {
            float2 p0 = sred[0][tid], p1 = sred[1][tid];
            float M = fmaxf(p0.x, p1.x);
            float S = p0.y * __expf(p0.x - M) + p1.y * __expf(p1.x - M);
            if (p == 0)
                headP[(size_t)(tau * 128 + tid) * HEAD_CHUNKS + chunk] = make_float2(M, S);
            else
                tailP[(size_t)(tokBase + tau * 128 + tid) * TAILP_STRIDE + chunk] = make_float2(M, S);
        }

        if (!hasNext) break;
        k = nk; item = nitem;
        Wb = nWb; Hb = nHb;
        p = np; chunk = nchunk; tau = ntau; tokBase = ntokBase; rowBase = nrowBase;
    }
}

// ---------------- merge partials -> nll ----------------
__global__ __launch_bounds__(256) void k_stageB(
    const float2* __restrict__ headP, const float2* __restrict__ tailP,
    const float2* __restrict__ stash, const int* __restrict__ target,
    const int* __restrict__ inv, float* __restrict__ out)
{
    const int wave = threadIdx.x >> 6, lane = threadIdx.x & 63;
    const int t = blockIdx.x * 4 + wave;
    const int tg = target[t];
    const int ci = (tg >= 5000) + (tg >= 15000) + (tg >= 30000);

    float m = -1e30f, s = 0.f;
    if (lane < HEAD_CHUNKS) { float2 p = headP[(size_t)t * HEAD_CHUNKS + lane]; m = p.x; s = p.y; }
    #pragma unroll
    for (int off = 1; off < 64; off <<= 1) {
        float m2 = __shfl_xor(m, off, 64);
        float s2 = __shfl_xor(s, off, 64);
        float M = fmaxf(m, m2);
        s = s * __expf(m - M) + s2 * __expf(m2 - M);
        m = M;
    }
    float2 st = stash[t];
    float nll = (m + __logf(s)) - st.x;

    if (ci) {
        const int nch_[4] = {0, 79, 118, 159};
        const int nch = nch_[ci];
        const int pos = inv[t];
        float m2 = -1e30f, s2 = 0.f;
        for (int c = lane; c < nch; c += 64) {
            float2 p = tailP[(size_t)pos * TAILP_STRIDE + c];
            float M = fmaxf(m2, p.x);
            s2 = s2 * __expf(m2 - M) + p.y * __expf(p.x - M);
            m2 = M;
        }
        #pragma unroll
        for (int off = 1; off < 64; off <<= 1) {
            float mm = __shfl_xor(m2, off, 64);
            float ss = __shfl_xor(s2, off, 64);
            float M = fmaxf(m2, mm);
            s2 = s2 * __expf(m2 - M) + ss * __expf(mm - M);
            m2 = M;
        }
        nll += (m2 + __logf(s2)) - st.y;
    }
    if (lane == 0) out[t] = nll;
}

extern "C" void kernel_launch(void* const* d_in, const int* in_sizes, int n_in,
                              void* d_out, int out_size, void* d_ws, size_t ws_size,
                              hipStream_t stream) {
    const float* hidden  = (const float*)d_in[0];
    const int*   targetp = (const int*)d_in[1];
    const float* weight  = (const float*)d_in[2];
    const float* biasp   = (const float*)d_in[3];
    const float* cweight = (const float*)d_in[4];
    const float* cbias   = (const float*)d_in[5];
    float* outp = (float*)d_out;

    char* ws = (char*)d_ws;
    unsigned char* wsW   = (unsigned char*)(ws);                   // 25,952,256 B (fp8 permuted-in-window)
    float*         wsB   = (float*)(ws + 25952256);                //    202,752 B
    unsigned char* wsH   = (unsigned char*)(ws + 26155008);        //  2,097,152 B
    unsigned char* wsHc  = (unsigned char*)(ws + 28252160);        //  2,424,832 B
    float2*        headP = (float2*)(ws + 30676992);               //  1,310,720 B
    float2*        tailP = (float2*)(ws + 31987712);               //  6,062,080 B
    float2*        wsS   = (float2*)(ws + 38049792);               //     32,768 B
    int*           perm  = (int*)(ws + 38082560);                  //     18,944 B
    int*           inv   = (int*)(ws + 38101504);                  //     16,384 B
    int*           meta  = (int*)(ws + 38117888);                  //         64 B

    k_bucket<<<1, 256, 0, stream>>>(targetp, perm, inv, meta);
    k_convert<<<STASH_BASE + NTOK / 2, 128, 0, stream>>>(
        weight, biasp, cweight, cbias, hidden, perm, targetp,
        wsW, wsB, wsH, wsHc, wsS);
    k_gemm_all<<<GRID_PERSIST, 256, 0, stream>>>(wsW, wsB, wsH, wsHc, headP, tailP, meta);
    k_stageB<<<NTOK / 4, 256, 0, stream>>>(headP, tailP, wsS, targetp, inv, outp);
}

// Round 20
// 120.557 us; speedup vs baseline: 4.3722x; 1.0017x over previous
//
#include <hip/hip_runtime.h>

// Adaptive softmax NLL — fp8(e4m3)-MFMA persistent GEMM, 4 blocks/CU,
// XCD-contiguous items, workspace-baked 8B-unit permutation (0 LDS conflicts),
// COUNTED-VMCNT pipeline: per K-step raw s_barrier pairs + s_waitcnt vmcnt(4)
// (tile t+1's loads stay in flight across barriers; 1 full drain per item).
// Target/routing logits exact fp32 (stash fused into k_convert).
//
// Weight chunks (128 rows x 512B): head 40, t1 79, t2 118, t3 159 (pad w=0,
// bias=-1e30, vanishes in exp-weighted LSE merges).
// Work item = (partition, chunk, token-tile), exact list, persistent CTAs.

#define D 512
#define NROWS_PAD 50688
#define NTOK 4096
#define NTOKP 4736
#define HEAD_CHUNKS 40
#define TAILP_STRIDE 160
#define GRID_PERSIST 1024

typedef __attribute__((ext_vector_type(4))) float f32x4;

__device__ __forceinline__ unsigned f2fp8(float f) {
    // f32 -> OCP e4m3fn, RNE, saturate to 448
    unsigned u = __float_as_uint(f);
    unsigned s = (u >> 24) & 0x80u;
    unsigned a = u & 0x7FFFFFFFu;
    if (a >= 0x43E00000u) return s | 0x7Eu;          // >= 448 -> sat
    if (a < 0x3C800000u) {                            // < 2^-6 -> subnormal
        int n = __float2int_rn(__uint_as_float(a) * 512.f);
        return s | (unsigned)n;
    }
    unsigned lsb = (a >> 20) & 1u;
    a += 0x7FFFFu + lsb;                              // RNE at bit 20
    unsigned e = (a >> 23) - 120u;
    unsigned m = (a >> 20) & 7u;
    if (e >= 16u || (e == 15u && m == 7u)) return s | 0x7Eu;
    return s | (e << 3) | m;
}

__device__ __forceinline__ void gload_lds16(const void* g, void* l) {
    __builtin_amdgcn_global_load_lds(
        (const __attribute__((address_space(1))) unsigned int*)g,
        (__attribute__((address_space(3))) unsigned int*)l, 16, 0, 0);
}

// ---------------- bucket tokens by cluster (deterministic counting sort) ----------------
__global__ __launch_bounds__(256) void k_bucket(
    const int* __restrict__ target, int* __restrict__ perm,
    int* __restrict__ inv, int* __restrict__ meta)
{
    __shared__ int cnt[256][4];
    __shared__ int basesh[256][4];
    __shared__ int sTot[4], sOff[4];
    const int th = threadIdx.x;
    for (int p = th; p < NTOKP; p += 256) perm[p] = -1;
    int lc[4] = {0, 0, 0, 0};
    #pragma unroll
    for (int i = 0; i < 16; ++i) {
        int tg = target[th * 16 + i];
        int c = (tg >= 5000) + (tg >= 15000) + (tg >= 30000);
        lc[c]++;
    }
    #pragma unroll
    for (int c = 0; c < 4; ++c) cnt[th][c] = lc[c];
    __syncthreads();
    if (th < 4) {
        int tot = 0;
        for (int i = 0; i < 256; ++i) tot += cnt[i][th];
        sTot[th] = tot;
    }
    __syncthreads();
    if (th == 0) {
        int b = 0;
        for (int c = 1; c < 4; ++c) { sOff[c] = b; b += ((sTot[c] + 127) >> 7) << 7; }
        meta[0] = sTot[1]; meta[1] = sTot[2]; meta[2] = sTot[3];
        meta[3] = sOff[1]; meta[4] = sOff[2]; meta[5] = sOff[3];
        meta[6] = (sTot[1] + 127) >> 7;
        meta[7] = (sTot[2] + 127) >> 7;
        meta[8] = (sTot[3] + 127) >> 7;
    }
    __syncthreads();
    if (th >= 1 && th < 4) {
        int run = sOff[th];
        for (int i = 0; i < 256; ++i) { basesh[i][th] = run; run += cnt[i][th]; }
    }
    __syncthreads();
    int run[4];
    #pragma unroll
    for (int c = 1; c < 4; ++c) run[c] = basesh[th][c];
    for (int i = 0; i < 16; ++i) {
        int t = th * 16 + i;
        int tg = target[t];
        int c = (tg >= 5000) + (tg >= 15000) + (tg >= 30000);
        if (c > 0) { int pos = run[c]++; perm[pos] = t; inv[t] = pos; }
        else inv[t] = -1;
    }
}

// ---------------- convert to fp8 (permuted-in-window, full-line writes) + fused stash ----------------
// Dest u32 index within row: kt*16 + ((u_s ^ vr) * 2) + half, u_s=(i&15)>>1,
// half=i&1, kt=i>>4, vr=(r128>>1)&7. Permutation stays inside each 64B line.
#define STASH_BASE (NROWS_PAD + NTOK + NTOKP)
__global__ __launch_bounds__(128) void k_convert(
    const float* __restrict__ weight, const float* __restrict__ bias,
    const float* __restrict__ cweight, const float* __restrict__ cbias,
    const float* __restrict__ hidden, const int* __restrict__ perm,
    const int* __restrict__ target,
    unsigned char* __restrict__ wsW, float* __restrict__ wsB,
    unsigned char* __restrict__ wsH, unsigned char* __restrict__ wsHc,
    float2* __restrict__ stash)
{
    const int r = blockIdx.x;
    const int i = threadIdx.x;   // 0..127
    if (r >= STASH_BASE) {
        // fused exact-fp32 stash: 2 waves/block, one token each
        const int wave = i >> 6, lane = i & 63;
        const int t = (r - STASH_BASE) * 2 + wave;
        const int tg = target[t];
        const int ci = (tg >= 5000) + (tg >= 15000) + (tg >= 30000);
        const float4* h = (const float4*)(hidden + (size_t)t * D);
        const float4* w = (const float4*)(weight + (size_t)tg * D);
        const float4* c = (const float4*)(cweight + (size_t)(ci ? 3 - ci : 0) * D);
        float dw = 0.f, dc = 0.f;
        #pragma unroll
        for (int u = 0; u < 2; ++u) {
            float4 hh = h[lane * 2 + u];
            float4 ww = w[lane * 2 + u];
            float4 cc = c[lane * 2 + u];
            dw += hh.x * ww.x + hh.y * ww.y + hh.z * ww.z + hh.w * ww.w;
            dc += hh.x * cc.x + hh.y * cc.y + hh.z * cc.z + hh.w * cc.w;
        }
        #pragma unroll
        for (int off = 1; off < 64; off <<= 1) {
            dw += __shfl_xor(dw, off, 64);
            dc += __shfl_xor(dc, off, 64);
        }
        if (lane == 0) {
            float head = ci ? dc + cbias[3 - ci] : dw + bias[tg];
            float tail = ci ? dw + bias[tg]      : 0.f;
            stash[t] = make_float2(head, tail);
        }
        return;
    }
    float4 v = make_float4(0.f, 0.f, 0.f, 0.f);
    unsigned* dst;
    int r128;
    if (r < NROWS_PAD) {
        const int pstart[4] = {0, 5120, 15232, 30336};
        const int plen[4]   = {5003, 10000, 15000, 20257};
        const int psrc[4]   = {0, 5000, 15000, 30000};
        int p = (r < 5120) ? 0 : (r < 15232) ? 1 : (r < 30336) ? 2 : 3;
        int o = r - pstart[p];
        const float* src = nullptr;
        float b = -1e30f;
        if (o < plen[p]) {
            if (p == 0 && o >= 5000) { src = cweight + (size_t)(o - 5000) * D; b = cbias[o - 5000]; }
            else { int sr = psrc[p] + o; src = weight + (size_t)sr * D; b = bias[sr]; }
        }
        if (src) v = ((const float4*)src)[i];
        if (i == 0) wsB[r] = b;
        dst = (unsigned*)(wsW + (size_t)r * D);
        r128 = r & 127;
    } else if (r < NROWS_PAD + NTOK) {
        int hr = r - NROWS_PAD;
        v = ((const float4*)(hidden + (size_t)hr * D))[i];
        dst = (unsigned*)(wsH + (size_t)hr * D);
        r128 = hr & 127;
    } else {
        int p = r - NROWS_PAD - NTOK;       // compacted position
        int tok = perm[p];
        if (tok >= 0) v = ((const float4*)(hidden + (size_t)tok * D))[i];
        dst = (unsigned*)(wsHc + (size_t)p * D);
        r128 = p & 127;
    }
    unsigned pk = f2fp8(v.x) | (f2fp8(v.y) << 8) | (f2fp8(v.z) << 16) | (f2fp8(v.w) << 24);
    const int vr = (r128 >> 1) & 7;
    const int iw = (i >> 4) * 16 + ((((i & 15) >> 1) ^ vr) << 1) + (i & 1);
    dst[iw] = pk;
}

// ---------------- persistent fp8 GEMM: 128x128, BK=64, counted-vmcnt pipeline ----------------
// Per K-step t: [t==0: stage tile1] wait vmcnt(4) -> barrier -> MFMA(buf t&1)
// -> barrier -> stage tile t+2 (t<6) / next-item tile0 (t==6). Tile t+1's 4
// loads remain in flight across both barriers. One full drain per item (top).
__global__ __launch_bounds__(256, 4) void k_gemm_all(
    const unsigned char* __restrict__ wsW, const float* __restrict__ wsB,
    const unsigned char* __restrict__ wsH, const unsigned char* __restrict__ wsHc,
    float2* __restrict__ headP, float2* __restrict__ tailP,
    const int* __restrict__ meta)
{
    const int nt1 = meta[6], nt2 = meta[7], nt3 = meta[8];
    const int base1 = meta[3], base2 = meta[4], base3 = meta[5];
    const int b1 = HEAD_CHUNKS * 32;
    const int b2 = b1 + 79 * nt1;
    const int b3 = b2 + 118 * nt2;
    const int b4 = b3 + 159 * nt3;

    const int tid = threadIdx.x;
    const int w = tid >> 6, lane = tid & 63;
    const int wm = w >> 1, wn = w & 1;
    const int lm = lane & 15, kg = lane >> 4;
    const int v8 = (lm >> 1) & 7;              // per-lane unit-XOR (row ≡ lm mod 16)
    const int rowA = wm * 64 + lm;
    const int rowB = wn * 64 + lm;
    const int koff0 = ((0 * 4 + kg) ^ v8) * 8; // ks=0 fragment byte offset in 64B window
    const int koff1 = ((1 * 4 + kg) ^ v8) * 8; // ks=1

    __shared__ __align__(16) unsigned char ldsA[2][8192];   // 128 rows x 64 B (fp8, BK=64)
    __shared__ __align__(16) unsigned char ldsB[2][8192];
    __shared__ float2 sred[2][128];

    auto decode = [&](int it, const unsigned char*& Wb, const unsigned char*& Hb,
                      int& p, int& chunk, int& tau, int& tokBase, int& rowBase) {
        if (it < b1)      { p = 0; chunk = it >> 5;          tau = it & 31;                 tokBase = 0; }
        else if (it < b2) { p = 1; int x = it - b1; chunk = x / nt1; tau = x - chunk * nt1; tokBase = base1; }
        else if (it < b3) { p = 2; int x = it - b2; chunk = x / nt2; tau = x - chunk * nt2; tokBase = base2; }
        else              { p = 3; int x = it - b3; chunk = x / nt3; tau = x - chunk * nt3; tokBase = base3; }
        const int pchunk_[4] = {0, 40, 119, 237};
        rowBase = (pchunk_[p] + chunk) * 128;
        Wb = wsW + (size_t)rowBase * D;
        Hb = (p == 0 ? wsH + (size_t)(tau * 128) * D
                     : wsHc + (size_t)(tokBase + tau * 128) * D);
    };

    auto STAGE = [&](const unsigned char* Wb, const unsigned char* Hb, int buf, int kt) {
        #pragma unroll
        for (int j = 0; j < 2; ++j) {
            int e = j * 256 + tid;              // linear 16-B granule copy, 0..511
            int r = e >> 2;                     // row 0..127
            size_t go = (size_t)r * D + (size_t)kt * 64 + (e & 3) * 16;
            gload_lds16(Wb + go, &ldsA[buf][e * 16]);
            gload_lds16(Hb + go, &ldsB[buf][e * 16]);
        }
    };

    // XCD-contiguous item slice
    const int nper = (b4 + 7) >> 3;
    const int xcd = blockIdx.x & 7;
    const int slot = blockIdx.x >> 3;          // 0..127 slots per XCD
    int k = slot;
    int item = xcd * nper + k;
    if (k >= nper || item >= b4) return;

    const unsigned char *Wb, *Hb;
    int p, chunk, tau, tokBase, rowBase;
    decode(item, Wb, Hb, p, chunk, tau, tokBase, rowBase);
    STAGE(Wb, Hb, 0, 0);

    while (true) {
        const int nk = k + 128;
        const int nitem = xcd * nper + nk;
        const bool hasNext = (nk < nper) && (nitem < b4);
        const unsigned char *nWb = nullptr, *nHb = nullptr;
        int np, nchunk, ntau, ntokBase, nrowBase;
        if (hasNext) decode(nitem, nWb, nHb, np, nchunk, ntau, ntokBase, nrowBase);

        f32x4 acc[4][4];
        #pragma unroll
        for (int m = 0; m < 4; ++m)
            #pragma unroll
            for (int n = 0; n < 4; ++n) acc[m][n] = (f32x4){0.f, 0.f, 0.f, 0.f};

        __syncthreads();   // per-item full drain: tile0 landed, sred reusable

        for (int t = 0; t < 8; ++t) {
            const int buf = t & 1;
            if (t == 0) STAGE(Wb, Hb, 1, 1);          // tile1 into buf1
            if (t == 7 && !hasNext)
                asm volatile("s_waitcnt vmcnt(0)" ::: "memory");
            else
                asm volatile("s_waitcnt vmcnt(4)" ::: "memory");  // oldest 4 = tile t
            __builtin_amdgcn_s_barrier();
            asm volatile("" ::: "memory");

            const char* bA = (const char*)&ldsA[buf][0];
            const char* bB = (const char*)&ldsB[buf][0];
            #pragma unroll
            for (int ks = 0; ks < 2; ++ks) {
                const int koff = ks ? koff1 : koff0;
                long af[4], bf8[4];
                #pragma unroll
                for (int m = 0; m < 4; ++m)
                    af[m] = *(const long*)(bA + (rowA + m * 16) * 64 + koff);
                #pragma unroll
                for (int n = 0; n < 4; ++n)
                    bf8[n] = *(const long*)(bB + (rowB + n * 16) * 64 + koff);
                #pragma unroll
                for (int m = 0; m < 4; ++m)
                    #pragma unroll
                    for (int n = 0; n < 4; ++n)
                        acc[m][n] = __builtin_amdgcn_mfma_f32_16x16x32_fp8_fp8(
                            af[m], bf8[n], acc[m][n], 0, 0, 0);
            }

            asm volatile("" ::: "memory");
            __builtin_amdgcn_s_barrier();             // all waves done reading buf
            asm volatile("" ::: "memory");
            if (t < 6) STAGE(Wb, Hb, buf, t + 2);     // refill freed buffer
            else if (t == 6 && hasNext) STAGE(nWb, nHb, 0, 0);  // next item tile0
        }

        // ---- epilogue: bias + per-token LSE over this chunk's 128 rows ----
        f32x4 bb[4];
        #pragma unroll
        for (int m = 0; m < 4; ++m)
            bb[m] = *(const f32x4*)(wsB + rowBase + wm * 64 + m * 16 + kg * 4);

        #pragma unroll
        for (int n = 0; n < 4; ++n) {
            float mval = -1e30f;
            #pragma unroll
            for (int m = 0; m < 4; ++m)
                #pragma unroll
                for (int j = 0; j < 4; ++j) {
                    acc[m][n][j] += bb[m][j];
                    mval = fmaxf(mval, acc[m][n][j]);
                }
            float sval = 0.f;
            #pragma unroll
            for (int m = 0; m < 4; ++m)
                #pragma unroll
                for (int j = 0; j < 4; ++j)
                    sval += __expf(acc[m][n][j] - mval);
            #pragma unroll
            for (int off = 16; off < 64; off <<= 1) {
                float m2 = __shfl_xor(mval, off, 64);
                float s2 = __shfl_xor(sval, off, 64);
                float M = fmaxf(mval, m2);
                sval = sval * __expf(mval - M) + s2 * __expf(m2 - M);
                mval = M;
            }
            if (lane < 16)
                sred[wm][wn * 64 + n * 16 + lane] = make_float2(mval, sval);
        }
        __syncthreads();
        if (tid < 128) {
            float2 p0 = sred[0][tid], p1 = sred[1][tid];
            float M = fmaxf(p0.x, p1.x);
            float S = p0.y * __expf(p0.x - M) + p1.y * __expf(p1.x - M);
            if (p == 0)
                headP[(size_t)(tau * 128 + tid) * HEAD_CHUNKS + chunk] = make_float2(M, S);
            else
                tailP[(size_t)(tokBase + tau * 128 + tid) * TAILP_STRIDE + chunk] = make_float2(M, S);
        }

        if (!hasNext) break;
        k = nk; item = nitem;
        Wb = nWb; Hb = nHb;
        p = np; chunk = nchunk; tau = ntau; tokBase = ntokBase; rowBase = nrowBase;
    }
}

// ---------------- merge partials -> nll ----------------
__global__ __launch_bounds__(256) void k_stageB(
    const float2* __restrict__ headP, const float2* __restrict__ tailP,
    const float2* __restrict__ stash, const int* __restrict__ target,
    const int* __restrict__ inv, float* __restrict__ out)
{
    const int wave = threadIdx.x >> 6, lane = threadIdx.x & 63;
    const int t = blockIdx.x * 4 + wave;
    const int tg = target[t];
    const int ci = (tg >= 5000) + (tg >= 15000) + (tg >= 30000);

    float m = -1e30f, s = 0.f;
    if (lane < HEAD_CHUNKS) { float2 p = headP[(size_t)t * HEAD_CHUNKS + lane]; m = p.x; s = p.y; }
    #pragma unroll
    for (int off = 1; off < 64; off <<= 1) {
        float m2 = __shfl_xor(m, off, 64);
        float s2 = __shfl_xor(s, off, 64);
        float M = fmaxf(m, m2);
        s = s * __expf(m - M) + s2 * __expf(m2 - M);
        m = M;
    }
    float2 st = stash[t];
    float nll = (m + __logf(s)) - st.x;

    if (ci) {
        const int nch_[4] = {0, 79, 118, 159};
        const int nch = nch_[ci];
        const int pos = inv[t];
        float m2 = -1e30f, s2 = 0.f;
        for (int c = lane; c < nch; c += 64) {
            float2 p = tailP[(size_t)pos * TAILP_STRIDE + c];
            float M = fmaxf(m2, p.x);
            s2 = s2 * __expf(m2 - M) + p.y * __expf(p.x - M);
            m2 = M;
        }
        #pragma unroll
        for (int off = 1; off < 64; off <<= 1) {
            float mm = __shfl_xor(m2, off, 64);
            float ss = __shfl_xor(s2, off, 64);
            float M = fmaxf(m2, mm);
            s2 = s2 * __expf(m2 - M) + ss * __expf(mm - M);
            m2 = M;
        }
        nll += (m2 + __logf(s2)) - st.y;
    }
    if (lane == 0) out[t] = nll;
}

extern "C" void kernel_launch(void* const* d_in, const int* in_sizes, int n_in,
                              void* d_out, int out_size, void* d_ws, size_t ws_size,
                              hipStream_t stream) {
    const float* hidden  = (const float*)d_in[0];
    const int*   targetp = (const int*)d_in[1];
    const float* weight  = (const float*)d_in[2];
    const float* biasp   = (const float*)d_in[3];
    const float* cweight = (const float*)d_in[4];
    const float* cbias   = (const float*)d_in[5];
    float* outp = (float*)d_out;

    char* ws = (char*)d_ws;
    unsigned char* wsW   = (unsigned char*)(ws);                   // 25,952,256 B (fp8 permuted-in-window)
    float*         wsB   = (float*)(ws + 25952256);                //    202,752 B
    unsigned char* wsH   = (unsigned char*)(ws + 26155008);        //  2,097,152 B
    unsigned char* wsHc  = (unsigned char*)(ws + 28252160);        //  2,424,832 B
    float2*        headP = (float2*)(ws + 30676992);               //  1,310,720 B
    float2*        tailP = (float2*)(ws + 31987712);               //  6,062,080 B
    float2*        wsS   = (float2*)(ws + 38049792);               //     32,768 B
    int*           perm  = (int*)(ws + 38082560);                  //     18,944 B
    int*           inv   = (int*)(ws + 38101504);                  //     16,384 B
    int*           meta  = (int*)(ws + 38117888);                  //         64 B

    k_bucket<<<1, 256, 0, stream>>>(targetp, perm, inv, meta);
    k_convert<<<STASH_BASE + NTOK / 2, 128, 0, stream>>>(
        weight, biasp, cweight, cbias, hidden, perm, targetp,
        wsW, wsB, wsH, wsHc, wsS);
    k_gemm_all<<<GRID_PERSIST, 256, 0, stream>>>(wsW, wsB, wsH, wsHc, headP, tailP, meta);
    k_stageB<<<NTOK / 4, 256, 0, stream>>>(headP, tailP, wsS, targetp, inv, outp);
}